// Round 6
// baseline (757.946 us; speedup 1.0000x reference)
//
#include <hip/hip_runtime.h>

// Light-field per-pixel 9x9 filter, R6.
// out[b,s,o,h,w] = clip(sum_{i,ky,kx} lf[b,s,i,3h-3+ky,3w-3+kx] * W[s,o,i,h,w,81] + bias, 0, 1)
//
// R5 post-mortem: 81-reg lf patch spilled (VGPR 256, WRITE 857MB). R4 (194us)
// was TA-bound: 729 scalar lf gathers/thread (~8 lines each). R6: lf patch in
// LDS, cooperatively filled with dense float4 loads (9/thread/i), prefetched
// T14-style during the previous phase; compute is pure ds_read+fma (no masks).
// Window = 128 floats from x0=96wq-4: 16B-aligned, chunks never straddle the
// 0/384 boundary (pad 4 = chunk 4) -> fully-valid-or-fully-zero chunks.
// Weights keep R4's dbuf global_load_lds staging.

#define ST 9
#define INC 3
#define OUTC 3
#define OHH 128
#define OWW 128
#define KDIM 9
#define KK 81
#define HH 384
#define WW 384
#define HWSZ (HH*WW)          // 147456
#define WQ 32                 // w columns per block
#define SLICE (WQ*KK)         // 2592 floats = 10368 B
#define NPH (INC*OUTC)        // 9 phases
#define LFW 128               // lf window floats per (b,ky) row

__device__ __forceinline__ void gll16(const float* g, float* l) {
  __builtin_amdgcn_global_load_lds((const __attribute__((address_space(1))) void*)g,
                                   (__attribute__((address_space(3))) void*)l, 16, 0, 0);
}

__global__ __launch_bounds__(128) void lf_filter_kernel(
    const float* __restrict__ lf, const float* __restrict__ wts,
    const float* __restrict__ bias, float* __restrict__ out)
{
  __shared__ __align__(16) float ldsW[2][SLICE];        // 20736 B
  __shared__ __align__(16) float ldsLF[4*KDIM*LFW];     // 18432 B -> total 39168 B

  const int t   = threadIdx.x;
  const int wl  = t & 31;          // w within quarter (also fill col)
  const int b   = t >> 5;          // batch (also fill row-batch)
  const int bid = blockIdx.x;
  const int wq  = bid & 3;
  const int h   = (bid >> 2) & 127;
  const int s   = bid >> 9;
  const int w   = wq*WQ + wl;
  const int ybase = 3*h - 3;

  const float* lfb = lf + (size_t)(b*ST + s)*INC*HWSZ;

  // lf fill geometry: chunk col = wl, x0q multiple of 4, never straddles borders
  const int  x0q = 96*wq - 4 + 4*wl;
  const bool xv  = (unsigned)x0q <= 380u;

  const int wu = (t & ~63) * 4;    // wave-uniform LDS dest offset (dwords)

  auto stage_w = [&](int p, int bufsel) {
    const int i = p / OUTC, o = p % OUTC;
    const float* wsrc = wts + ((size_t)(((s*OUTC + o)*INC + i)*OHH + h)*OWW + wq*WQ)*KK;
    float* dst = ldsW[bufsel];
    #pragma unroll
    for (int j = 0; j < 5; ++j)
      gll16(wsrc + (size_t)(j*128 + t)*4, dst + j*512 + wu);
    if (t < 8)
      gll16(wsrc + (size_t)(640 + t)*4, dst + 2560 + wu);
  };

  float4 pre[KDIM];                // 36 VGPRs: one window row per ky
  auto lf_load = [&](int i) {      // issue 9 float4 global loads (in flight)
    const float* src = lfb + (size_t)i*HWSZ + x0q;
    #pragma unroll
    for (int j = 0; j < KDIM; ++j) {
      const int y = ybase + j;     // block-uniform
      float4 v = make_float4(0.f, 0.f, 0.f, 0.f);
      if (((unsigned)y < (unsigned)HH) && xv)
        v = *reinterpret_cast<const float4*>(src + (size_t)y*WW);
      pre[j] = v;
    }
  };
  auto lf_commit = [&]() {         // regs -> LDS
    float4* dst = reinterpret_cast<float4*>(ldsLF) + (b*KDIM)*(LFW/4) + wl;
    #pragma unroll
    for (int j = 0; j < KDIM; ++j) dst[j*(LFW/4)] = pre[j];
  };

  float acc[OUTC] = {0.f, 0.f, 0.f};

  // prologue: weight slice 0 via gll, lf(0) via regs -> LDS, one drain
  stage_w(0, 0);
  lf_load(0);
  lf_commit();
  __syncthreads();

  #pragma unroll
  for (int p = 0; p < NPH; ++p) {
    const int o = p % OUTC;
    if (p + 1 < NPH) stage_w(p + 1, (p + 1) & 1);          // async, in flight
    const bool ldpre = (o == OUTC - 1) && (p + 1 < NPH);
    if (ldpre) lf_load(p / OUTC + 1);                      // regs, in flight

    // ---- compute phase p: pure LDS + FMA ----
    const float* wrow = &ldsW[p & 1][wl*KK];               // stride 81: conflict-free
    const float* lrow = &ldsLF[(b*KDIM)*LFW + 3*wl + 1];   // stride 3: conflict-free
    float a0 = 0.f, a1 = 0.f, a2 = 0.f;
    #pragma unroll
    for (int ky = 0; ky < KDIM; ++ky) {
      #pragma unroll
      for (int kx = 0; kx < KDIM; ++kx) {
        const float lv = lrow[ky*LFW + kx];
        const float wv = wrow[ky*KDIM + kx];
        if (kx % 3 == 0)      a0 = fmaf(lv, wv, a0);
        else if (kx % 3 == 1) a1 = fmaf(lv, wv, a1);
        else                  a2 = fmaf(lv, wv, a2);
      }
    }
    acc[o] += (a0 + a1) + a2;

    if (p + 1 < NPH) __syncthreads();       // drains gll + pre loads; bufs ready
    if (ldpre) { lf_commit(); __syncthreads(); }   // publish lf(i+1)
  }

  // ---- epilogue: bias + clip + coalesced stores ----
  #pragma unroll
  for (int o = 0; o < OUTC; ++o) {
    const float bv = bias[((s*OUTC + o)*OHH + h)*OWW + w];
    float r = acc[o] + bv;
    r = r < 0.f ? 0.f : (r > 1.f ? 1.f : r);
    out[(((size_t)(b*ST + s)*OUTC + o)*OHH + h)*OWW + w] = r;
  }
}

extern "C" void kernel_launch(void* const* d_in, const int* in_sizes, int n_in,
                              void* d_out, int out_size, void* d_ws, size_t ws_size,
                              hipStream_t stream) {
  const float* lf   = (const float*)d_in[0];
  const float* wts  = (const float*)d_in[1];
  const float* bias = (const float*)d_in[2];
  float* out = (float*)d_out;
  dim3 grid(ST * OHH * 4);   // 4608 blocks: (s, h, w-quarter)
  dim3 block(128);           // (w:32) x (batch:4)
  hipLaunchKernelGGL(lf_filter_kernel, grid, block, 0, stream, lf, wts, bias, out);
}